// Round 1
// baseline (74.476 us; speedup 1.0000x reference)
//
#include <hip/hip_runtime.h>
#include <hip/hip_bf16.h>

// SemiPool2d max-plus: out[b,c,p,q] = max_{i<7,j<7}( x[b,c,2p+i,2q+j] + w[c,i,j] )
// x: (8,64,224,224) f32, w: (1,64,7,7) f32, out: (8,64,109,109) f32

#define BB 8
#define CC 64
#define HH 224
#define WW 224
#define MM 7
#define NN 7
#define SS 2
#define HO 109
#define WO 109
#define TOTAL (BB*CC*HO*WO)

__global__ __launch_bounds__(256) void semipool_kernel(
    const float* __restrict__ x,
    const float* __restrict__ w,
    float* __restrict__ out)
{
    int idx = blockIdx.x * 256 + threadIdx.x;
    if (idx >= TOTAL) return;

    int q = idx % WO;
    int t = idx / WO;
    int p = t % HO;
    t /= HO;
    int c = t % CC;
    int b = t / CC;

    const float* __restrict__ xp = x + (((b * CC + c) * HH + p * SS) * WW + q * SS);
    const float* __restrict__ wp = w + c * (MM * NN);

    float m = -1e30f;
#pragma unroll
    for (int i = 0; i < MM; ++i) {
#pragma unroll
        for (int j = 0; j < NN; ++j) {
            m = fmaxf(m, xp[i * WW + j] + wp[i * NN + j]);
        }
    }
    out[idx] = m;
}

extern "C" void kernel_launch(void* const* d_in, const int* in_sizes, int n_in,
                              void* d_out, int out_size, void* d_ws, size_t ws_size,
                              hipStream_t stream) {
    const float* x = (const float*)d_in[0];
    const float* w = (const float*)d_in[1];
    float* out = (float*)d_out;

    int blocks = (TOTAL + 255) / 256;
    semipool_kernel<<<blocks, 256, 0, stream>>>(x, w, out);
}

// Round 2
// 37.396 us; speedup vs baseline: 1.9916x; 1.9916x over previous
//
#include <hip/hip_runtime.h>
#include <hip/hip_bf16.h>

// SemiPool2d max-plus: out[b,c,p,q] = max_{i<7,j<7}( x[b,c,2p+i,2q+j] + w[c,i,j] )
// x: (8,64,224,224) f32, w: (1,64,7,7) f32, out: (8,64,109,109) f32
//
// Each thread computes a PT x QT = 4x4 output tile.
// Input rows are loaded as 7 aligned float2 (col base 2*q0 is always even ->
// 8B aligned; avoids misalignment from WO=109 odd tails). Tail tiles clamp
// p0/q0 to 105 and recompute overlapping outputs (identical values, benign).

#define BB 8
#define CC 64
#define HH 224
#define WW 224
#define HO 109
#define WO 109
#define PT 4
#define QT 4
#define NPB 28   // ceil(109/4)
#define NQB 28
// total threads = 8*64*28*28 = 401408 = 1568 * 256

__global__ __launch_bounds__(256) void semipool_kernel(
    const float* __restrict__ x,
    const float* __restrict__ w,
    float* __restrict__ out)
{
    int tg = blockIdx.x * 256 + threadIdx.x;

    int qb = tg % NQB;
    int t  = tg / NQB;
    int pb = t % NPB;
    t /= NPB;
    int c = t % CC;
    int b = t / CC;

    int q0 = qb * QT; if (q0 > WO - QT) q0 = WO - QT;   // <= 105
    int p0 = pb * PT; if (p0 > HO - PT) p0 = HO - PT;   // <= 105

    // weights for this channel: 49 values in registers
    const float* __restrict__ wp = w + c * 49;
    float wr[7][7];
#pragma unroll
    for (int i = 0; i < 7; ++i)
#pragma unroll
        for (int j = 0; j < 7; ++j)
            wr[i][j] = wp[i * 7 + j];

    float acc[PT][QT];
#pragma unroll
    for (int a = 0; a < PT; ++a)
#pragma unroll
        for (int d = 0; d < QT; ++d)
            acc[a][d] = -1e30f;

    const float* __restrict__ xbase =
        x + (((b * CC + c) * HH) + p0 * 2) * WW + q0 * 2;

    // 13 input rows feed the 4 output rows (stride 2, kernel 7)
#pragma unroll
    for (int r = 0; r < 2 * (PT - 1) + 7; ++r) {   // r = 0..12
        const float* __restrict__ row = xbase + r * WW;
        float xr[14];
#pragma unroll
        for (int k = 0; k < 7; ++k) {
            float2 v = *reinterpret_cast<const float2*>(row + 2 * k);
            xr[2 * k]     = v.x;
            xr[2 * k + 1] = v.y;
        }
#pragma unroll
        for (int pp = 0; pp < PT; ++pp) {
            int i = r - 2 * pp;              // compile-time after unroll
            if (i >= 0 && i < 7) {
#pragma unroll
                for (int qq = 0; qq < QT; ++qq)
#pragma unroll
                    for (int j = 0; j < 7; ++j)
                        acc[pp][qq] = fmaxf(acc[pp][qq], xr[2 * qq + j] + wr[i][j]);
            }
        }
    }

#pragma unroll
    for (int pp = 0; pp < PT; ++pp) {
        float* __restrict__ orow = out + ((b * CC + c) * HO + (p0 + pp)) * WO + q0;
#pragma unroll
        for (int qq = 0; qq < QT; ++qq)
            orow[qq] = acc[pp][qq];
    }
}

extern "C" void kernel_launch(void* const* d_in, const int* in_sizes, int n_in,
                              void* d_out, int out_size, void* d_ws, size_t ws_size,
                              hipStream_t stream) {
    const float* x = (const float*)d_in[0];
    const float* w = (const float*)d_in[1];
    float* out = (float*)d_out;

    int total = BB * CC * NPB * NQB;          // 401408
    int blocks = (total + 255) / 256;          // 1568
    semipool_kernel<<<blocks, 256, 0, stream>>>(x, w, out);
}

// Round 4
// 33.860 us; speedup vs baseline: 2.1995x; 1.1044x over previous
//
#include <hip/hip_runtime.h>
#include <hip/hip_bf16.h>

// SemiPool2d max-plus: out[b,c,p,q] = max_{i<7,j<7}( x[b,c,2p+i,2q+j] + w[c,i,j] )
// x: (8,64,224,224) f32, w: (1,64,7,7) f32, out: (8,64,109,109) f32
//
// 4x4 output tile per thread. q-tiles padded 28->32 so tiles per (b,c) =
// 32*28 = 896 (multiple of 64): every wave is uniform in (b,c), so the 49
// weights are wave-uniform -> forced into SGPRs via readfirstlane (s_load),
// costing zero VGPRs and zero vector-load instructions. Clamped edge tiles
// recompute identical values (benign).

#define BB 8
#define CC 64
#define HH 224
#define WW 224
#define HO 109
#define WO 109
#define PT 4
#define QT 4
#define NPB 28   // ceil(109/4)
#define NQB 32   // padded from 28 to 32 -> 896 tiles per (b,c), mult of 64
// total threads = 8*64*28*32 = 458752 = 1792 * 256

__global__ __launch_bounds__(256) void semipool_kernel(
    const float* __restrict__ x,
    const float* __restrict__ w,
    float* __restrict__ out)
{
    int tg = blockIdx.x * 256 + threadIdx.x;

    int qb = tg & 31;          // NQB = 32 (pow2)
    int t  = tg >> 5;
    int pb = t % NPB;
    t = t / NPB;               // t = b*CC + c, wave-uniform by construction

    int q0 = qb * QT; if (q0 > WO - QT) q0 = WO - QT;   // <= 105
    int p0 = pb * PT; if (p0 > HO - PT) p0 = HO - PT;   // <= 105

    // (b*64+c) is identical across the 64 lanes of a wave (896 tiles per
    // channel, 64 | 896). readfirstlane makes it an SGPR so w loads become
    // scalar loads and x/out bases become SGPR+voffset addressing.
    int bc = __builtin_amdgcn_readfirstlane(t);

    // 49 channel weights -> SGPRs (uniform address, scalar loads)
    const float* __restrict__ wp = w + (bc & (CC - 1)) * 49;
    float wr[49];
#pragma unroll
    for (int k = 0; k < 49; ++k) wr[k] = wp[k];

    float acc[PT][QT];
#pragma unroll
    for (int a = 0; a < PT; ++a)
#pragma unroll
        for (int d = 0; d < QT; ++d)
            acc[a][d] = -1e30f;

    const float* __restrict__ xbase =
        x + (bc * HH + p0 * 2) * WW + q0 * 2;

    // 13 input rows feed the 4 output rows (stride 2, kernel 7)
#pragma unroll
    for (int r = 0; r < 2 * (PT - 1) + 7; ++r) {   // r = 0..12
        const float* __restrict__ row = xbase + r * WW;
        float xr[14];
#pragma unroll
        for (int k = 0; k < 7; ++k) {
            float2 v = *reinterpret_cast<const float2*>(row + 2 * k);
            xr[2 * k]     = v.x;
            xr[2 * k + 1] = v.y;
        }
#pragma unroll
        for (int pp = 0; pp < PT; ++pp) {
            int i = r - 2 * pp;              // compile-time after unroll
            if (i >= 0 && i < 7) {
#pragma unroll
                for (int qq = 0; qq < QT; ++qq)
#pragma unroll
                    for (int j = 0; j < 7; ++j)
                        acc[pp][qq] = fmaxf(acc[pp][qq], xr[2 * qq + j] + wr[i * 7 + j]);
            }
        }
    }

#pragma unroll
    for (int pp = 0; pp < PT; ++pp) {
        float* __restrict__ orow = out + (bc * HO + (p0 + pp)) * WO + q0;
#pragma unroll
        for (int qq = 0; qq < QT; ++qq)
            orow[qq] = acc[pp][qq];
    }
}

extern "C" void kernel_launch(void* const* d_in, const int* in_sizes, int n_in,
                              void* d_out, int out_size, void* d_ws, size_t ws_size,
                              hipStream_t stream) {
    const float* x = (const float*)d_in[0];
    const float* w = (const float*)d_in[1];
    float* out = (float*)d_out;

    int total = BB * CC * NPB * NQB;           // 458752
    int blocks = total / 256;                  // 1792
    semipool_kernel<<<blocks, 256, 0, stream>>>(x, w, out);
}